// Round 3
// baseline (285.663 us; speedup 1.0000x reference)
//
#include <hip/hip_runtime.h>
#include <math.h>

#define WSZ 11
#define SCALE 1073741824.0   // 2^30 fixed-point for deterministic atomic sum
#define NPIX 12582912.0      // 16*3*512*512

struct GaussW { float g[WSZ]; };

// H-blur one row position for 5 fields (a, b, a^2, b^2, ab).
// CG: 0 = interior (no column guard), -1 = left edge wave, +1 = right edge wave.
template<int CG>
__device__ __forceinline__ void hblur_row(
    const float* __restrict__ rowA, const float* __restrict__ rowB,
    int c, const GaussW& W,
    float& o0, float& o1, float& o2, float& o3, float& o4)
{
    float s0 = 0.f, s1 = 0.f, s2 = 0.f, s3 = 0.f, s4 = 0.f;
#pragma unroll
    for (int j = 0; j < WSZ; ++j) {
        const int cc = c + j - 5;
        float aa, bb;
        if (CG == 0) {
            aa = rowA[cc];
            bb = rowB[cc];
        } else if (CG < 0) {
            const int ci = cc < 0 ? 0 : cc;       // clamp address, mask value
            aa = (cc < 0) ? 0.f : rowA[ci];
            bb = (cc < 0) ? 0.f : rowB[ci];
        } else {
            const int ci = cc > 511 ? 511 : cc;
            aa = (cc > 511) ? 0.f : rowA[ci];
            bb = (cc > 511) ? 0.f : rowB[ci];
        }
        const float w = W.g[j];
        const float wa = w * aa, wb = w * bb;
        s0 += wa;
        s1 += wb;
        s2 = fmaf(wa, aa, s2);
        s3 = fmaf(wb, bb, s3);
        s4 = fmaf(wa, bb, s4);
    }
    o0 = s0; o1 = s1; o2 = s2; o3 = s3; o4 = s4;
}

// One output row: fill ring slot (10+p)%11 with H-blur of row gr, then V-blur.
// p must be a compile-time constant after unrolling (static ring indices).
template<int CG>
__device__ __forceinline__ void step(
    const float* __restrict__ baseA, const float* __restrict__ baseB,
    int c, int gr, int p, const GaussW& W,
    float (&h0)[WSZ], float (&h1)[WSZ], float (&h2)[WSZ],
    float (&h3)[WSZ], float (&h4)[WSZ], float& local)
{
    const int sn = (10 + p) % WSZ;
    if (gr < 512) {            // wave-uniform; lower bound impossible here
        hblur_row<CG>(baseA + gr * 512, baseB + gr * 512, c, W,
                      h0[sn], h1[sn], h2[sn], h3[sn], h4[sn]);
    } else {
        h0[sn] = 0.f; h1[sn] = 0.f; h2[sn] = 0.f; h3[sn] = 0.f; h4[sn] = 0.f;
    }

    float mu1 = 0.f, mu2 = 0.f, e11 = 0.f, e22 = 0.f, e12 = 0.f;
#pragma unroll
    for (int k = 0; k < WSZ; ++k) {
        const int s = (p + k) % WSZ;    // constant after unroll
        const float w = W.g[k];
        mu1 = fmaf(w, h0[s], mu1);
        mu2 = fmaf(w, h1[s], mu2);
        e11 = fmaf(w, h2[s], e11);
        e22 = fmaf(w, h3[s], e22);
        e12 = fmaf(w, h4[s], e12);
    }
    const float mu1sq = mu1 * mu1;
    const float mu2sq = mu2 * mu2;
    const float mu12  = mu1 * mu2;
    const float s11 = e11 - mu1sq;
    const float s22 = e22 - mu2sq;
    const float s12 = e12 - mu12;
    const float num = (2.f * mu12 + 1e-4f) * (2.f * s12 + 9e-4f);
    const float den = (mu1sq + mu2sq + 1e-4f) * (s11 + s22 + 9e-4f);
    float rr = __builtin_amdgcn_rcpf(den);
    rr = rr * (2.f - den * rr);          // one NR step
    local = fmaf(num, rr, local);
}

// 64 output rows for one column. Ring prologue (10 rows) + 5x11 main + 9 tail.
template<int CG>
__device__ float do_strip(const float* __restrict__ baseA,
                          const float* __restrict__ baseB,
                          int c, int r0, const GaussW& W)
{
    float h0[WSZ], h1[WSZ], h2[WSZ], h3[WSZ], h4[WSZ];

#pragma unroll
    for (int p = 0; p < 10; ++p) {
        const int gr = r0 - 5 + p;
        if (gr >= 0) {                  // top edge only (gr <= 457 here)
            hblur_row<CG>(baseA + gr * 512, baseB + gr * 512, c, W,
                          h0[p], h1[p], h2[p], h3[p], h4[p]);
        } else {
            h0[p] = 0.f; h1[p] = 0.f; h2[p] = 0.f; h3[p] = 0.f; h4[p] = 0.f;
        }
    }

    float local = 0.f;
    for (int ii = 0; ii < 5; ++ii) {    // dynamic outer: keeps code ~11 bodies
        const int gb = r0 + 5 + ii * 11;
#pragma unroll
        for (int p = 0; p < 11; ++p)
            step<CG>(baseA, baseB, c, gb + p, p, W, h0, h1, h2, h3, h4, local);
    }
#pragma unroll
    for (int p = 0; p < 9; ++p)         // i = 55..63; 55 % 11 == 0 so same p-phase
        step<CG>(baseA, baseB, c, r0 + 60 + p, p, W, h0, h1, h2, h3, h4, local);

    return local;
}

__global__ __launch_bounds__(256, 3) void ssim_main(
    const float* __restrict__ img1, const float* __restrict__ img2,
    unsigned long long* __restrict__ acc, GaussW W)
{
    __shared__ float red[4];
    const int tid = threadIdx.x;
    const int lane = tid & 63;
    const int wv = tid >> 6;
    const int bx = blockIdx.x;          // 0..15 : 2 col-halves * 8 row-strips
    const int plane = blockIdx.y;       // 0..47
    const int c0w = (bx & 1) * 256 + wv * 64;   // wave's first column
    const int r0 = (bx >> 1) * 64;
    const int c = c0w + lane;

    const float* baseA = img1 + (size_t)plane * 262144;
    const float* baseB = img2 + (size_t)plane * 262144;

    float local;
    if (c0w == 0)        local = do_strip<-1>(baseA, baseB, c, r0, W);
    else if (c0w == 448) local = do_strip< 1>(baseA, baseB, c, r0, W);
    else                 local = do_strip< 0>(baseA, baseB, c, r0, W);

#pragma unroll
    for (int off = 32; off; off >>= 1)
        local += __shfl_down(local, off, 64);
    if (lane == 0) red[wv] = local;
    __syncthreads();
    if (tid == 0) {
        const float bs = red[0] + red[1] + red[2] + red[3];
        const unsigned long long q =
            (unsigned long long)__double2ll_rn((double)bs * SCALE);
        atomicAdd(acc, q);
    }
}

__global__ void ssim_final(const unsigned long long* __restrict__ acc,
                           float* __restrict__ out)
{
    if (threadIdx.x == 0)
        out[0] = (float)((double)(*acc) * (1.0 / SCALE) / NPIX);
}

extern "C" void kernel_launch(void* const* d_in, const int* in_sizes, int n_in,
                              void* d_out, int out_size, void* d_ws, size_t ws_size,
                              hipStream_t stream) {
    const float* img1 = (const float*)d_in[0];
    const float* img2 = (const float*)d_in[1];
    float* out = (float*)d_out;
    unsigned long long* acc = (unsigned long long*)d_ws;

    GaussW W;
    double g[WSZ], sum = 0.0;
    for (int i = 0; i < WSZ; ++i) {
        double d = (double)(i - 5);
        g[i] = exp(-(d * d) / 4.5);
        sum += g[i];
    }
    for (int i = 0; i < WSZ; ++i) W.g[i] = (float)(g[i] / sum);

    hipMemsetAsync(d_ws, 0, sizeof(unsigned long long), stream);
    ssim_main<<<dim3(16, 48), 256, 0, stream>>>(img1, img2, acc, W);
    ssim_final<<<1, 64, 0, stream>>>(acc, out);
}

// Round 4
// 77.078 us; speedup vs baseline: 3.7062x; 3.7062x over previous
//
#include <hip/hip_runtime.h>
#include <math.h>

typedef float v2 __attribute__((ext_vector_type(2)));

#define SCALE 1073741824.0   // 2^30 fixed-point for deterministic atomic sum
#define NPIX 12582912.0      // 16*3*512*512
#define C1f 1e-4f
#define C2f 9e-4f

struct Wts {
    float w[11];   // V-pass weights
    v2 hp[12];     // H-pass pair weights for element e=j+1: (w[j]|0, w[j-1]|0)
};

__device__ __forceinline__ v2 sp(float x) { v2 r; r.x = x; r.y = x; return r; }
__device__ __forceinline__ v2 f2(v2 a, v2 b, v2 c) {
    return __builtin_elementwise_fma(a, b, c);
}

__global__ __launch_bounds__(256) void ssim_main(
    const float* __restrict__ img1, const float* __restrict__ img2,
    unsigned long long* __restrict__ acc, Wts W)
{
    __shared__ float red[4];
    const int tid = threadIdx.x;
    const int lane = tid & 63;
    const int wv = tid >> 6;
    const int r0 = blockIdx.x * 32;            // 16 row-strips
    const int plane = blockIdx.y;              // 48 planes
    const int c = wv * 128 + 2 * lane;         // columns c, c+1

    const float* baseA = img1 + (size_t)plane * 262144;
    const float* baseB = img2 + (size_t)plane * 262144;

    // per-lane clamped chunk offsets (7 x float2 chunks covering [c-6, c+8))
    int off[7];
#pragma unroll
    for (int k = 0; k < 7; ++k) {
        int o = c - 6 + 2 * k;
        off[k] = o < 0 ? 0 : (o > 510 ? 510 : o);
    }
    // per-lane H weight pairs, zeroed where element column is out of image
    v2 hpl[12];
#pragma unroll
    for (int j = 0; j < 12; ++j) {
        const int col = c - 5 + j;
        const bool ok = (col >= 0) && (col < 512);
        hpl[j] = ok ? W.hp[j] : sp(0.f);
    }

    v2 rS[11], rD[11], rP[11], rM[11];         // ring: blurred u, v, u^2, v^2
    v2 loc = sp(0.f);
    v2 a[7], b[7];

    const float* rowA = baseA + (r0 - 5) * 512;
    const float* rowB = baseB + (r0 - 5) * 512;
    int gr = r0 - 5;

    auto LOAD = [&]() {
#pragma unroll
        for (int k = 0; k < 7; ++k) {
            a[k] = *(const v2*)(rowA + off[k]);
            b[k] = *(const v2*)(rowB + off[k]);
        }
    };
    auto HPUSH = [&](int p) {   // p is compile-time constant at each call site
        v2 hS = sp(0.f), hD = sp(0.f), hP = sp(0.f), hM = sp(0.f);
#pragma unroll
        for (int j = 0; j < 12; ++j) {
            const int e = j + 1;                     // element in [c-6, c+8)
            const float xa = (e & 1) ? a[e >> 1].y : a[e >> 1].x;
            const float xb = (e & 1) ? b[e >> 1].y : b[e >> 1].x;
            const float u = xa + xb, v = xa - xb;
            const float uu = u * u, vv = v * v;
            hS = f2(hpl[j], sp(u),  hS);
            hD = f2(hpl[j], sp(v),  hD);
            hP = f2(hpl[j], sp(uu), hP);
            hM = f2(hpl[j], sp(vv), hM);
        }
        rS[p] = hS; rD[p] = hD; rP[p] = hP; rM[p] = hM;
    };
    auto ZPUSH = [&](int p) {
        rS[p] = sp(0.f); rD[p] = sp(0.f); rP[p] = sp(0.f); rM[p] = sp(0.f);
    };
    auto VOUT = [&](int p) {    // output row t; ring holds its 11 window rows
        v2 S = sp(0.f), D = sp(0.f), P = sp(0.f), M = sp(0.f);
#pragma unroll
        for (int k = 0; k < 11; ++k) {
            const int q = (p + k) % 11;              // constant after unroll
            const v2 wk = sp(W.w[k]);
            S = f2(wk, rS[q], S);
            D = f2(wk, rD[q], D);
            P = f2(wk, rP[q], P);
            M = f2(wk, rM[q], M);
        }
        const v2 ss = S * S, dd = D * D;
        const v2 mu12  = (ss - dd) * sp(0.25f);      // mu1*mu2
        const v2 musq  = (ss + dd) * sp(0.5f);       // mu1^2 + mu2^2
        const v2 sig12 = (P - M) * sp(0.25f) - mu12; // E[ab] - mu1mu2
        const v2 sigsm = (P + M) * sp(0.5f) - musq;  // sig1^2 + sig2^2
        const v2 num = (sp(2.f) * mu12 + sp(C1f)) * (sp(2.f) * sig12 + sp(C2f));
        const v2 den = (musq + sp(C1f)) * (sigsm + sp(C2f));
        v2 r;
        r.x = __builtin_amdgcn_rcpf(den.x);
        r.y = __builtin_amdgcn_rcpf(den.y);
        r = r * (sp(2.f) - den * r);                 // one NR step
        loc = f2(num, r, loc);
    };
    auto ADV = [&]() { rowA += 512; rowB += 512; ++gr; };

    // ---- prologue: window rows s=0..10 (global rows r0-5 .. r0+5) ----
#pragma unroll
    for (int p = 0; p < 11; ++p) {
        if ((unsigned)gr < 512u) { LOAD(); HPUSH(p); } else ZPUSH(p);
        ADV();
    }
    // ---- main: s=11..32, outputs t=0..21 ----
    for (int bq = 0; bq < 2; ++bq) {
#pragma unroll
        for (int p = 0; p < 11; ++p) {
            if ((unsigned)gr < 512u) { LOAD(); VOUT(p); HPUSH(p); }
            else                     { VOUT(p); ZPUSH(p); }
            ADV();
        }
    }
    // ---- tail: s=33..41, outputs t=22..30 ----
#pragma unroll
    for (int p = 0; p < 9; ++p) {
        if ((unsigned)gr < 512u) { LOAD(); VOUT(p); HPUSH(p); }
        else                     { VOUT(p); ZPUSH(p); }
        ADV();
    }
    // ---- final: s=42, output t=31 (V only) ----
    VOUT(9);

    // ---- reduction -> fixed-point global atomic ----
    float l = loc.x + loc.y;
#pragma unroll
    for (int o2 = 32; o2; o2 >>= 1)
        l += __shfl_down(l, o2, 64);
    if (lane == 0) red[wv] = l;
    __syncthreads();
    if (tid == 0) {
        const float bs = red[0] + red[1] + red[2] + red[3];
        const unsigned long long q =
            (unsigned long long)__double2ll_rn((double)bs * SCALE);
        atomicAdd(acc, q);
    }
}

__global__ void ssim_final(const unsigned long long* __restrict__ acc,
                           float* __restrict__ out)
{
    if (threadIdx.x == 0)
        out[0] = (float)((double)(*acc) * (1.0 / SCALE) / NPIX);
}

extern "C" void kernel_launch(void* const* d_in, const int* in_sizes, int n_in,
                              void* d_out, int out_size, void* d_ws, size_t ws_size,
                              hipStream_t stream) {
    const float* img1 = (const float*)d_in[0];
    const float* img2 = (const float*)d_in[1];
    float* out = (float*)d_out;
    unsigned long long* acc = (unsigned long long*)d_ws;

    double g[11], ssum = 0.0;
    for (int i = 0; i < 11; ++i) {
        const double d = (double)(i - 5);
        g[i] = exp(-(d * d) / 4.5);
        ssum += g[i];
    }
    Wts W;
    for (int i = 0; i < 11; ++i) W.w[i] = (float)(g[i] / ssum);
    for (int j = 0; j < 12; ++j) {
        v2 p;
        p.x = (j <= 10) ? W.w[j] : 0.f;      // out0 weight for element j+1
        p.y = (j >= 1) ? W.w[j - 1] : 0.f;   // out1 weight for element j+1
        W.hp[j] = p;
    }

    hipMemsetAsync(d_ws, 0, sizeof(unsigned long long), stream);
    ssim_main<<<dim3(16, 48), 256, 0, stream>>>(img1, img2, acc, W);
    ssim_final<<<1, 64, 0, stream>>>(acc, out);
}